// Round 4
// baseline (91362.683 us; speedup 1.0000x reference)
//
#include <hip/hip_runtime.h>
#include <hip/hip_cooperative_groups.h>

namespace cg = cooperative_groups;

typedef short v8s __attribute__((ext_vector_type(8)));
typedef float v4f __attribute__((ext_vector_type(4)));

#define T_SEQ 512
#define BATCH 64
#define NH    1024
#define TC    16   // time-chunk length (G buffer covers TC steps)

__device__ __forceinline__ ushort f2bf(float f) {
    union { float f; unsigned int i; } v; v.f = f;
    unsigned int x = v.i;
    return (ushort)((x + 0x7fffu + ((x >> 16) & 1u)) >> 16);
}
__device__ __forceinline__ float sigm(float x) { return 1.0f / (1.0f + __expf(-x)); }
__device__ __forceinline__ float tanhx(float x) {
    float e = __expf(2.0f * x);           // inf-safe: x>>0 -> 1, x<<0 -> -1
    return 1.0f - 2.0f / (e + 1.0f);
}
// convert 8 consecutive fp32 -> 8 bf16 packed as int4, store to LDS/regs dst
__device__ __forceinline__ void stage8_f32(ushort* dst, const float* src) {
    float4 a = *(const float4*)src;
    float4 b = *(const float4*)(src + 4);
    ushort t[8] = {f2bf(a.x), f2bf(a.y), f2bf(a.z), f2bf(a.w),
                   f2bf(b.x), f2bf(b.y), f2bf(b.z), f2bf(b.w)};
    *(int4*)dst = *(int4*)t;
}
__device__ __forceinline__ v8s load8_f32(const float* src) {
    float4 a = *(const float4*)src;
    float4 b = *(const float4*)(src + 4);
    ushort t[8] = {f2bf(a.x), f2bf(a.y), f2bf(a.z), f2bf(a.w),
                   f2bf(b.x), f2bf(b.y), f2bf(b.z), f2bf(b.w)};
    return *(v8s*)t;
}

// ---------------------------------------------------------------------------
// Input-projection GEMM: G[(s*64+b)*4096 + j] = sum_k A(s,b,k)*W[j][k] + bias[j]
// A sources are fp32 except the circular hf chunk (bf16).
// mode 0: A = X[(b*512 + tstart + s*tstep)*1024 + k]                 (K=1024)
// mode 1: k<1024 : hfc[(((tstart+s)&15)*64 + b)*1024 + k]   (bf16 circular)
//         k>=1024: enc[(b*512 + tstart+s)*1024 + (k-1024)]  (fp32 hb in enc)
// 128x128 tile, 256 threads (4 waves, 2x2), 16x16x32 bf16 MFMA, fp32 out.
// ---------------------------------------------------------------------------
__global__ __launch_bounds__(256)
void gates_gemm(const float* __restrict__ A0f, const ushort* __restrict__ A0h,
                const float* __restrict__ A1f,
                const float* __restrict__ W, const float* __restrict__ bias,
                float* __restrict__ G, int tstart, int tstep, int K, int mode)
{
    __shared__ ushort As[128][32];
    __shared__ ushort Bs[128][32];
    const int tid  = threadIdx.x;
    const int lane = tid & 63;
    const int wave = tid >> 6;
    const int wm   = (wave >> 1) * 64;
    const int wn   = (wave & 1) * 64;
    const int r    = lane & 15;
    const int q    = lane >> 4;
    const int tm   = blockIdx.x;   // M tiles, M = TC*BATCH = 1024
    const int tn   = blockIdx.y;   // N tiles, N = 4096

    v4f acc[4][4] = {};

    const int nkb = K >> 5;
    for (int kb = 0; kb < nkb; ++kb) {
        const int k0 = kb << 5;
        __syncthreads();   // protect previous iter's frag reads
        #pragma unroll
        for (int j = 0; j < 2; ++j) {
            int c   = tid * 2 + j;
            int row = c >> 2;
            int k8  = (c & 3) << 3;
            int kg  = k0 + k8;
            // stage A
            int m = tm * 128 + row;
            int s = m >> 6, b = m & 63;
            if (mode == 0) {
                int t = tstart + s * tstep;
                stage8_f32(&As[row][k8], A0f + ((size_t)b * T_SEQ + t) * NH + kg);
            } else {
                int t = tstart + s;
                if (kg < NH) {
                    *(int4*)(&As[row][k8]) =
                        *(const int4*)(A0h + (((size_t)(t & (TC - 1)) * BATCH) + b) * NH + kg);
                } else {
                    stage8_f32(&As[row][k8], A1f + ((size_t)b * T_SEQ + t) * NH + (kg - NH));
                }
            }
            // stage B (W rows are j, contiguous in k -> already B^T form)
            int jr = tn * 128 + row;
            stage8_f32(&Bs[row][k8], W + (size_t)jr * K + kg);
        }
        __syncthreads();
        v8s af[4], bfv[4];
        #pragma unroll
        for (int i = 0; i < 4; ++i) af[i]  = *(const v8s*)(&As[wm + i * 16 + r][q * 8]);
        #pragma unroll
        for (int i = 0; i < 4; ++i) bfv[i] = *(const v8s*)(&Bs[wn + i * 16 + r][q * 8]);
        #pragma unroll
        for (int i = 0; i < 4; ++i)
            #pragma unroll
            for (int jt = 0; jt < 4; ++jt)
                acc[i][jt] = __builtin_amdgcn_mfma_f32_16x16x32_bf16(af[i], bfv[jt], acc[i][jt], 0, 0, 0);
    }

    // epilogue: C/D layout col = lane&15 (n/j), row = q*4+reg (m)
    #pragma unroll
    for (int jt = 0; jt < 4; ++jt) {
        int j = tn * 128 + wn + jt * 16 + r;
        float bv = bias[j];
        #pragma unroll
        for (int i = 0; i < 4; ++i) {
            #pragma unroll
            for (int rr = 0; rr < 4; ++rr) {
                int m = tm * 128 + wm + i * 16 + q * 4 + rr;
                G[(size_t)m * 4096 + j] = acc[i][jt][rr] + bv;
            }
        }
    }
}

// ---------------------------------------------------------------------------
// Cooperative recurrence: 256 blocks = 64 hidden-tiles x 4 batch-tiles.
// Wave w (0..3) computes gate-type w (i,f,g,o) for [16 batch x 16 hidden],
// one 16x16x32 MFMA chain over K=1024 (h staged in LDS, Whh fp32 from L2,
// converted to bf16 on the fly). c-state in wave-0 registers (fp32).
// HF32=1: H is fp32 (enc region); HF32=0: H is bf16 (circular chunk buffer).
// H element (t,b,n) at (t & tmask)*stride_t + b*stride_b + n.
// ---------------------------------------------------------------------------
template<int HF32>
__global__ __launch_bounds__(256)
void lstm_recur(const float* __restrict__ G, const float* __restrict__ Whh,
                void* __restrict__ Hv, float* __restrict__ Cst,
                float* __restrict__ oHT, float* __restrict__ oCT,
                int tstart, int nsteps, int tstep, int stride_t, int stride_b,
                int tmask, int first, int tlast)
{
    __shared__ ushort hs[16][1032];       // +8 pad: spread LDS banks for b128 reads
    __shared__ float exch[3][16][17];     // f,g,o tiles -> wave 0
    cg::grid_group grid = cg::this_grid();

    float*  Hf = (float*)Hv;
    ushort* Hh = (ushort*)Hv;

    const int blk = blockIdx.x;
    const int n0  = (blk & 63) << 4;
    const int b0  = (blk >> 6) << 4;
    const int tid = threadIdx.x;
    const int lane = tid & 63;
    const int w    = tid >> 6;
    const int r    = lane & 15;
    const int q    = lane >> 4;

    float creg[4] = {0.f, 0.f, 0.f, 0.f};
    if (w == 0 && !first) {
        #pragma unroll
        for (int rr = 0; rr < 4; ++rr)
            creg[rr] = Cst[(size_t)(b0 + q * 4 + rr) * NH + n0 + r];
    }
    const float* wrow = Whh + (size_t)(w * NH + n0 + r) * NH + q * 8;

    for (int s = 0; s < nsteps; ++s) {
        const int t = tstart + s * tstep;
        v4f acc = {0.f, 0.f, 0.f, 0.f};
        const bool have_h = !(first && s == 0);
        if (have_h) {
            const int tp = t - tstep;
            const size_t hbase = (size_t)(tp & tmask) * stride_t;
            #pragma unroll
            for (int j = 0; j < 8; ++j) {          // stage h[16][1024] -> LDS (bf16)
                int c   = j * 256 + tid;
                int row = c >> 7;
                int k8  = (c & 127) << 3;
                size_t off = hbase + (size_t)(b0 + row) * stride_b + k8;
                if (HF32) stage8_f32(&hs[row][k8], Hf + off);
                else      *(int4*)(&hs[row][k8]) = *(const int4*)(Hh + off);
            }
        }
        __syncthreads();
        if (have_h) {
            #pragma unroll 8
            for (int kk = 0; kk < 32; ++kk) {
                v8s a = *(const v8s*)(&hs[r][kk * 32 + q * 8]);
                v8s b = load8_f32(wrow + kk * 32);
                acc = __builtin_amdgcn_mfma_f32_16x16x32_bf16(a, b, acc, 0, 0, 0);
            }
        }
        const float* gt = G + ((size_t)s * BATCH + b0) * 4096 + w * NH + n0;
        #pragma unroll
        for (int rr = 0; rr < 4; ++rr) acc[rr] += gt[(size_t)(q * 4 + rr) * 4096 + r];
        if (w > 0) {
            #pragma unroll
            for (int rr = 0; rr < 4; ++rr) exch[w - 1][q * 4 + rr][r] = acc[rr];
        }
        __syncthreads();
        if (w == 0) {
            #pragma unroll
            for (int rr = 0; rr < 4; ++rr) {
                int bl = q * 4 + rr;
                float iv = sigm(acc[rr]);
                float fv = sigm(exch[0][bl][r]);
                float gv = tanhx(exch[1][bl][r]);
                float ov = sigm(exch[2][bl][r]);
                float c  = fv * creg[rr] + iv * gv;
                creg[rr] = c;
                float h  = ov * tanhx(c);
                size_t hoff = (size_t)(t & tmask) * stride_t + (size_t)(b0 + bl) * stride_b + n0 + r;
                if (HF32) Hf[hoff] = h;
                else      Hh[hoff] = f2bf(h);
                if (oHT != nullptr && t == tlast) {
                    oHT[(size_t)(b0 + bl) * NH + n0 + r] = h;
                    oCT[(size_t)(b0 + bl) * NH + n0 + r] = c;
                }
            }
            __threadfence();
        }
        grid.sync();
    }
    if (w == 0) {
        #pragma unroll
        for (int rr = 0; rr < 4; ++rr)
            Cst[(size_t)(b0 + q * 4 + rr) * NH + n0 + r] = creg[rr];
    }
}

// ---------------------------------------------------------------------------
static void launch_recur(int hf32, const float* G, const float* Whh, void* H,
                         float* Cst, float* oHT, float* oCT,
                         int tstart, int nsteps, int tstep,
                         int stride_t, int stride_b, int tmask, int first, int tlast,
                         hipStream_t stream)
{
    void* args[14];
    args[0]  = (void*)&G;        args[1]  = (void*)&Whh;
    args[2]  = (void*)&H;        args[3]  = (void*)&Cst;
    args[4]  = (void*)&oHT;      args[5]  = (void*)&oCT;
    args[6]  = (void*)&tstart;   args[7]  = (void*)&nsteps;
    args[8]  = (void*)&tstep;    args[9]  = (void*)&stride_t;
    args[10] = (void*)&stride_b; args[11] = (void*)&tmask;
    args[12] = (void*)&first;    args[13] = (void*)&tlast;
    const void* fn = hf32 ? (const void*)&lstm_recur<1> : (const void*)&lstm_recur<0>;
    hipLaunchCooperativeKernel(fn, dim3(256), dim3(256), args, 0, stream);
}

extern "C" void kernel_launch(void* const* d_in, const int* in_sizes, int n_in,
                              void* d_out, int out_size, void* d_ws, size_t ws_size,
                              hipStream_t stream)
{
    const float* X     = (const float*)d_in[0];
    const float* Wf_ih = (const float*)d_in[1];
    const float* Wf_hh = (const float*)d_in[2];
    const float* bf_b  = (const float*)d_in[3];
    const float* Wb_ih = (const float*)d_in[4];
    const float* Wb_hh = (const float*)d_in[5];
    const float* bb_b  = (const float*)d_in[6];
    const float* Wc_ih = (const float*)d_in[7];
    const float* Wc_hh = (const float*)d_in[8];
    const float* bc_b  = (const float*)d_in[9];

    float* enc = (float*)d_out;                        // [B][T][N] fp32; hosts hb then enc
    float* oHT = enc + (size_t)BATCH * T_SEQ * NH;     // [B][N]
    float* oCT = oHT + (size_t)BATCH * NH;             // [B][N]

    // ws: G (16 MB) | hf_chunk bf16 (2 MB) | cstF | cstC | cstB  -> 18.75 MB
    char* ws = (char*)d_ws;
    const size_t G_BYTES  = (size_t)TC * BATCH * 4096 * 4;     // 16 MB
    const size_t HC_BYTES = (size_t)TC * BATCH * NH * 2;       // 2 MB
    const size_t C_BYTES  = (size_t)BATCH * NH * 4;            // 256 KB
    float*  G    = (float*)ws;
    ushort* hfc  = (ushort*)(ws + G_BYTES);                    // circular [t&15][b][n] bf16
    float*  cstF = (float*)(ws + G_BYTES + HC_BYTES);
    float*  cstC = (float*)(ws + G_BYTES + HC_BYTES + C_BYTES);
    float*  cstB = (float*)(ws + G_BYTES + HC_BYTES + 2 * C_BYTES);

    const int NCH = T_SEQ / TC;              // 32 chunks
    dim3 ggrid(TC * BATCH / 128, 32), gblk(256);
    const int FULLT = 0x7FFFFFFF;

    // 1) backward bilstm -> hb stored fp32 in enc region, [b][t][n] layout
    for (int c = 0; c < NCH; ++c) {
        int ts = T_SEQ - 1 - c * TC;
        gates_gemm<<<ggrid, gblk, 0, stream>>>(X, (const ushort*)nullptr, (const float*)nullptr,
                                               Wb_ih, bb_b, G, ts, -1, 1024, 0);
        launch_recur(1, G, Wb_hh, enc, cstB, nullptr, nullptr,
                     ts, TC, -1, NH, T_SEQ * NH, FULLT, c == 0 ? 1 : 0, -1, stream);
    }
    // 2) forward bilstm + cell LSTM interleaved per chunk.
    //    hf lives in the bf16 circular buffer; cell gemm chunk c consumes hb rows
    //    (t in chunk c) from enc BEFORE cell recur overwrites them with fp32 output.
    for (int c = 0; c < NCH; ++c) {
        int ts = c * TC;
        gates_gemm<<<ggrid, gblk, 0, stream>>>(X, (const ushort*)nullptr, (const float*)nullptr,
                                               Wf_ih, bf_b, G, ts, 1, 1024, 0);
        launch_recur(0, G, Wf_hh, hfc, cstF, nullptr, nullptr,
                     ts, TC, 1, BATCH * NH, NH, TC - 1, c == 0 ? 1 : 0, -1, stream);
        gates_gemm<<<ggrid, gblk, 0, stream>>>((const float*)nullptr, hfc, enc,
                                               Wc_ih, bc_b, G, ts, 1, 2048, 1);
        launch_recur(1, G, Wc_hh, enc, cstC, oHT, oCT,
                     ts, TC, 1, NH, T_SEQ * NH, FULLT, c == 0 ? 1 : 0, T_SEQ - 1, stream);
    }
}